// Round 1
// baseline (1363.330 us; speedup 1.0000x reference)
//
#include <hip/hip_runtime.h>

#define HD 128

__device__ __forceinline__ float lrelu(float x, float s) { return x > 0.f ? x : s * x; }

// ---------------- graph prep ----------------
__global__ void k_edge_count(const int* __restrict__ src, const int* __restrict__ dst,
                             int* __restrict__ degc, int* __restrict__ cnt, int E) {
  int e = blockIdx.x * blockDim.x + threadIdx.x;
  if (e < E) {
    atomicAdd(&degc[src[e]], 1);
    atomicAdd(&cnt[dst[e]], 1);
  }
}

__global__ void k_dinv(const int* __restrict__ degc, float* __restrict__ dinv, int n) {
  int i = blockIdx.x * blockDim.x + threadIdx.x;
  if (i < n) {
    int d = degc[i];
    dinv[i] = d > 0 ? rsqrtf((float)d) : 0.f;
  }
}

__global__ void k_scan(const int* __restrict__ cnt, int* __restrict__ rowptr,
                       int* __restrict__ wo, int n, int Etot) {
  __shared__ int buf[1024];
  __shared__ int carry_s;
  if (threadIdx.x == 0) carry_s = 0;
  __syncthreads();
  for (int base = 0; base < n; base += 1024) {
    int i = base + (int)threadIdx.x;
    int v = (i < n) ? cnt[i] : 0;
    buf[threadIdx.x] = v;
    __syncthreads();
    for (int o = 1; o < 1024; o <<= 1) {
      int t = (threadIdx.x >= (unsigned)o) ? buf[threadIdx.x - o] : 0;
      __syncthreads();
      buf[threadIdx.x] += t;
      __syncthreads();
    }
    int excl = carry_s + buf[threadIdx.x] - v;
    if (i < n) { rowptr[i] = excl; wo[i] = excl; }
    __syncthreads();
    if (threadIdx.x == 0) carry_s += buf[1023];
    __syncthreads();
  }
  if (threadIdx.x == 0) rowptr[n] = Etot;
}

__global__ void k_fill(const int* __restrict__ src, const int* __restrict__ dst,
                       int* __restrict__ wo, const float* __restrict__ dinv,
                       int* __restrict__ col, float* __restrict__ wgt, int E) {
  int e = blockIdx.x * blockDim.x + threadIdx.x;
  if (e < E) {
    int s = src[e], d = dst[e];
    int p = atomicAdd(&wo[d], 1);
    col[p] = s;
    wgt[p] = -dinv[s] * dinv[d];
  }
}

// ---------------- props ----------------
// F=3 prop: one thread per dst row
__global__ void k_prop3(const int* __restrict__ rowptr, const int* __restrict__ col,
                        const float* __restrict__ wgt, const float* __restrict__ Hs,
                        const float* __restrict__ Sub, float* __restrict__ Out,
                        float scale, int n) {
  int r = blockIdx.x * blockDim.x + threadIdx.x;
  if (r >= n) return;
  int b = rowptr[r], e = rowptr[r + 1];
  float a0 = 0.f, a1 = 0.f, a2 = 0.f;
  for (int j = b; j < e; ++j) {
    int s = col[j];
    float w = wgt[j];
    a0 = fmaf(w, Hs[s * 3 + 0], a0);
    a1 = fmaf(w, Hs[s * 3 + 1], a1);
    a2 = fmaf(w, Hs[s * 3 + 2], a2);
  }
  float r0 = scale * a0, r1 = scale * a1, r2 = scale * a2;
  if (Sub) { r0 -= Sub[r * 3 + 0]; r1 -= Sub[r * 3 + 1]; r2 -= Sub[r * 3 + 2]; }
  Out[r * 3 + 0] = r0; Out[r * 3 + 1] = r1; Out[r * 3 + 2] = r2;
}

// F=128 prop: one wave (64 lanes) per dst row, 2 features per lane
__global__ __launch_bounds__(256) void k_prop128(
    const int* __restrict__ rowptr, const int* __restrict__ col,
    const float* __restrict__ wgt, const float* __restrict__ Hs,
    const float* __restrict__ Sub, float* __restrict__ Out, float scale, int n) {
  int r = blockIdx.x * 4 + (int)(threadIdx.x >> 6);
  int lane = threadIdx.x & 63;
  if (r >= n) return;
  int b = rowptr[r], e = rowptr[r + 1];
  float a0 = 0.f, a1 = 0.f;
  int j = b;
  for (; j + 1 < e; j += 2) {
    int s0 = col[j], s1 = col[j + 1];
    float w0 = wgt[j], w1 = wgt[j + 1];
    const float* p0 = Hs + (size_t)s0 * HD;
    const float* p1 = Hs + (size_t)s1 * HD;
    a0 = fmaf(w0, p0[lane], a0);
    a1 = fmaf(w0, p0[64 + lane], a1);
    a0 = fmaf(w1, p1[lane], a0);
    a1 = fmaf(w1, p1[64 + lane], a1);
  }
  if (j < e) {
    int s0 = col[j];
    float w0 = wgt[j];
    const float* p0 = Hs + (size_t)s0 * HD;
    a0 = fmaf(w0, p0[lane], a0);
    a1 = fmaf(w0, p0[64 + lane], a1);
  }
  float r0 = scale * a0, r1 = scale * a1;
  if (Sub) {
    r0 -= Sub[(size_t)r * HD + lane];
    r1 -= Sub[(size_t)r * HD + 64 + lane];
  }
  Out[(size_t)r * HD + lane] = r0;
  Out[(size_t)r * HD + 64 + lane] = r1;
}

// ---------------- layer-1 fused gemm (fi=3, K=4) ----------------
__global__ void k_l1gemm(const float* __restrict__ X, const float* __restrict__ T1,
                         const float* __restrict__ T2, const float* __restrict__ T3,
                         const float* __restrict__ W1, const float* __restrict__ b1,
                         float* __restrict__ Out, int n) {
  int idx = blockIdx.x * blockDim.x + threadIdx.x;
  int r = idx >> 7, j = idx & 127;
  if (r >= n) return;
  float acc = b1[j];
#pragma unroll
  for (int c = 0; c < 3; ++c) {
    acc = fmaf(X [r * 3 + c], W1[0 * 3 * HD + c * HD + j], acc);
    acc = fmaf(T1[r * 3 + c], W1[1 * 3 * HD + c * HD + j], acc);
    acc = fmaf(T2[r * 3 + c], W1[2 * 3 * HD + c * HD + j], acc);
    acc = fmaf(T3[r * 3 + c], W1[3 * 3 * HD + c * HD + j], acc);
  }
  Out[(size_t)r * HD + j] = acc;
}

// ---------------- fp32 GEMM: C[n,128] (+)= A[n,128] @ W[128,128] ----------------
// block: 256 threads; tile 64 rows x 128 cols; BK=32; per-thread 4x8 accs
__global__ __launch_bounds__(256) void k_gemm128(
    const float* __restrict__ A, const float* __restrict__ W,
    const float* __restrict__ bias, float* __restrict__ C, int n, int init) {
  __shared__ float sA[64][36];   // row-major, +4 pad
  __shared__ float sW[32][128];
  int tid = threadIdx.x;
  int cg8 = (tid & 15) << 3;   // col start (16 groups * 8 cols)
  int rg4 = (tid >> 4) << 2;   // row start (16 groups * 4 rows)
  int row0 = blockIdx.x * 64;

  float acc[4][8];
#pragma unroll
  for (int i = 0; i < 4; ++i)
#pragma unroll
    for (int j = 0; j < 8; ++j) acc[i][j] = 0.f;

  for (int kc = 0; kc < 4; ++kc) {
#pragma unroll
    for (int p = 0; p < 2; ++p) {           // stage A: 64x32 = 512 float4
      int q = tid + p * 256;
      int ar = q >> 3;
      int ac = (q & 7) << 2;
      int gr = row0 + ar;
      float4 v = make_float4(0.f, 0.f, 0.f, 0.f);
      if (gr < n) v = *(const float4*)&A[(size_t)gr * HD + kc * 32 + ac];
      *(float4*)&sA[ar][ac] = v;
    }
#pragma unroll
    for (int p = 0; p < 4; ++p) {           // stage W: 32x128 = 1024 float4
      int q = tid + p * 256;
      int wr = q >> 5;
      int wc = (q & 31) << 2;
      *(float4*)&sW[wr][wc] = *(const float4*)&W[(size_t)(kc * 32 + wr) * HD + wc];
    }
    __syncthreads();
#pragma unroll
    for (int k = 0; k < 32; ++k) {
      float av[4];
      av[0] = sA[rg4 + 0][k];
      av[1] = sA[rg4 + 1][k];
      av[2] = sA[rg4 + 2][k];
      av[3] = sA[rg4 + 3][k];
      float4 w0 = *(const float4*)&sW[k][cg8];
      float4 w1 = *(const float4*)&sW[k][cg8 + 4];
      float wv[8] = {w0.x, w0.y, w0.z, w0.w, w1.x, w1.y, w1.z, w1.w};
#pragma unroll
      for (int i = 0; i < 4; ++i)
#pragma unroll
        for (int j = 0; j < 8; ++j) acc[i][j] = fmaf(av[i], wv[j], acc[i][j]);
    }
    __syncthreads();
  }

#pragma unroll
  for (int i = 0; i < 4; ++i) {
    int gr = row0 + rg4 + i;
    if (gr < n) {
      float* dp = &C[(size_t)gr * HD + cg8];
      if (init) {
        float4 o0, o1;
        o0.x = acc[i][0] + bias[cg8 + 0]; o0.y = acc[i][1] + bias[cg8 + 1];
        o0.z = acc[i][2] + bias[cg8 + 2]; o0.w = acc[i][3] + bias[cg8 + 3];
        o1.x = acc[i][4] + bias[cg8 + 4]; o1.y = acc[i][5] + bias[cg8 + 5];
        o1.z = acc[i][6] + bias[cg8 + 6]; o1.w = acc[i][7] + bias[cg8 + 7];
        *(float4*)dp = o0; *(float4*)(dp + 4) = o1;
      } else {
        float4 c0 = *(float4*)dp, c1 = *(float4*)(dp + 4);
        c0.x += acc[i][0]; c0.y += acc[i][1]; c0.z += acc[i][2]; c0.w += acc[i][3];
        c1.x += acc[i][4]; c1.y += acc[i][5]; c1.z += acc[i][6]; c1.w += acc[i][7];
        *(float4*)dp = c0; *(float4*)(dp + 4) = c1;
      }
    }
  }
}

// ---------------- batchnorm ----------------
__global__ __launch_bounds__(256) void k_bnstat(const float* __restrict__ Hb, float slope,
                                                float* __restrict__ bsum, float* __restrict__ bsq,
                                                int n) {
  int f = threadIdx.x & 127;
  int h = threadIdx.x >> 7;
  float s = 0.f, s2 = 0.f;
  for (int r = blockIdx.x * 2 + h; r < n; r += gridDim.x * 2) {
    float v = lrelu(Hb[(size_t)r * HD + f], slope);
    s += v;
    s2 = fmaf(v, v, s2);
  }
  __shared__ float ls[256], ls2[256];
  ls[threadIdx.x] = s; ls2[threadIdx.x] = s2;
  __syncthreads();
  if (threadIdx.x < 128) {
    atomicAdd(&bsum[f], ls[threadIdx.x] + ls[threadIdx.x + 128]);
    atomicAdd(&bsq[f], ls2[threadIdx.x] + ls2[threadIdx.x + 128]);
  }
}

__global__ void k_bnfin(const float* __restrict__ bsum, const float* __restrict__ bsq,
                        const float* __restrict__ g, const float* __restrict__ be,
                        float* __restrict__ scaleb, float* __restrict__ shiftb, int n) {
  int f = threadIdx.x;
  if (f < HD) {
    float m = bsum[f] / (float)n;
    float v = bsq[f] / (float)n - m * m;
    float rs = rsqrtf(v + 1e-5f);
    float sc = g[f] * rs;
    scaleb[f] = sc;
    shiftb[f] = be[f] - m * sc;
  }
}

__global__ void k_bnapply(const float* __restrict__ In, const float* __restrict__ scaleb,
                          const float* __restrict__ shiftb, float slope,
                          float* __restrict__ Outb, size_t total) {
  size_t i = (size_t)(blockIdx.x * blockDim.x + threadIdx.x) * 4;
  if (i >= total) return;
  float4 v = *(const float4*)&In[i];
  int f = (int)(i & 127);
  float4 o;
  o.x = fmaf(lrelu(v.x, slope), scaleb[f + 0], shiftb[f + 0]);
  o.y = fmaf(lrelu(v.y, slope), scaleb[f + 1], shiftb[f + 1]);
  o.z = fmaf(lrelu(v.z, slope), scaleb[f + 2], shiftb[f + 2]);
  o.w = fmaf(lrelu(v.w, slope), scaleb[f + 3], shiftb[f + 3]);
  *(float4*)&Outb[i] = o;
}

// ---------------- final: row L2-normalize + @Wr + br ----------------
__global__ __launch_bounds__(256) void k_final(const float* __restrict__ Hb,
                                               const float* __restrict__ Wr,
                                               const float* __restrict__ br,
                                               float* __restrict__ out, int n) {
  int r = blockIdx.x * 4 + (int)(threadIdx.x >> 6);
  int lane = threadIdx.x & 63;
  if (r >= n) return;
  float h0 = Hb[(size_t)r * HD + lane];
  float h1 = Hb[(size_t)r * HD + 64 + lane];
  float ss = h0 * h0 + h1 * h1;
#pragma unroll
  for (int o = 32; o; o >>= 1) ss += __shfl_xor(ss, o, 64);
  float inv = 1.f / fmaxf(sqrtf(ss), 1e-12f);
  h0 *= inv; h1 *= inv;
  float o0 = h0 * Wr[lane * 3 + 0] + h1 * Wr[(64 + lane) * 3 + 0];
  float o1 = h0 * Wr[lane * 3 + 1] + h1 * Wr[(64 + lane) * 3 + 1];
  float o2 = h0 * Wr[lane * 3 + 2] + h1 * Wr[(64 + lane) * 3 + 2];
#pragma unroll
  for (int o = 32; o; o >>= 1) {
    o0 += __shfl_xor(o0, o, 64);
    o1 += __shfl_xor(o1, o, 64);
    o2 += __shfl_xor(o2, o, 64);
  }
  if (lane == 0) {
    out[r * 3 + 0] = o0 + br[0];
    out[r * 3 + 1] = o1 + br[1];
    out[r * 3 + 2] = o2 + br[2];
  }
}

extern "C" void kernel_launch(void* const* d_in, const int* in_sizes, int n_in,
                              void* d_out, int out_size, void* d_ws, size_t ws_size,
                              hipStream_t stream) {
  const float* x  = (const float*)d_in[0];
  const int*   ei = (const int*)d_in[1];
  const float* W1 = (const float*)d_in[2];
  const float* b1 = (const float*)d_in[3];
  const float* W2 = (const float*)d_in[4];
  const float* b2 = (const float*)d_in[5];
  const float* W3 = (const float*)d_in[6];
  const float* b3 = (const float*)d_in[7];
  const float* W4 = (const float*)d_in[8];
  const float* b4 = (const float*)d_in[9];
  const float* g1 = (const float*)d_in[10];
  const float* be1= (const float*)d_in[11];
  const float* g2 = (const float*)d_in[12];
  const float* be2= (const float*)d_in[13];
  const float* g3 = (const float*)d_in[14];
  const float* be3= (const float*)d_in[15];
  const float* Wr = (const float*)d_in[16];
  const float* br = (const float*)d_in[17];

  const int N = in_sizes[0] / 3;
  const int E = in_sizes[1] / 2;
  const int* src = ei;
  const int* dst = ei + E;
  float* out = (float*)d_out;

  char* wp = (char*)d_ws;
  size_t used = 0;
  auto alloc = [&](size_t bytes) -> void* {
    void* p = (void*)(wp + used);
    used += (bytes + 255) & ~(size_t)255;
    return p;
  };
  int*   degc   = (int*)alloc((size_t)N * 4);
  int*   cnt    = (int*)alloc((size_t)N * 4);
  int*   rowptr = (int*)alloc((size_t)(N + 1) * 4);
  int*   wo     = (int*)alloc((size_t)N * 4);
  float* dinv   = (float*)alloc((size_t)N * 4);
  int*   col    = (int*)alloc((size_t)E * 4);
  float* wgt    = (float*)alloc((size_t)E * 4);
  float* t1     = (float*)alloc((size_t)N * 3 * 4);
  float* t2     = (float*)alloc((size_t)N * 3 * 4);
  float* t3     = (float*)alloc((size_t)N * 3 * 4);
  float* Ab     = (float*)alloc((size_t)N * HD * 4);
  float* Bb     = (float*)alloc((size_t)N * HD * 4);
  float* Cb     = (float*)alloc((size_t)N * HD * 4);
  float* OUT    = (float*)alloc((size_t)N * HD * 4);
  float* bnsum  = (float*)alloc(HD * 4);
  float* bnsq   = (float*)alloc(HD * 4);
  float* scaleb = (float*)alloc(HD * 4);
  float* shiftb = (float*)alloc(HD * 4);
  if (used > ws_size) return;  // workspace too small; fail loudly via wrong output

  const int eb = (E + 255) / 256;
  const int nb = (N + 255) / 256;
  const int pb = (N + 3) / 4;
  const int gb = (N + 63) / 64;

  hipMemsetAsync(degc, 0, (size_t)N * 4, stream);
  hipMemsetAsync(cnt, 0, (size_t)N * 4, stream);
  k_edge_count<<<eb, 256, 0, stream>>>(src, dst, degc, cnt, E);
  k_dinv<<<nb, 256, 0, stream>>>(degc, dinv, N);
  k_scan<<<1, 1024, 0, stream>>>(cnt, rowptr, wo, N, E);
  k_fill<<<eb, 256, 0, stream>>>(src, dst, wo, dinv, col, wgt, E);

  auto bn_act = [&](const float* g, const float* be, float slope) {
    hipMemsetAsync(bnsum, 0, HD * 4, stream);
    hipMemsetAsync(bnsq, 0, HD * 4, stream);
    k_bnstat<<<256, 256, 0, stream>>>(OUT, slope, bnsum, bnsq, N);
    k_bnfin<<<1, 128, 0, stream>>>(bnsum, bnsq, g, be, scaleb, shiftb, N);
    k_bnapply<<<((size_t)N * HD / 4 + 255) / 256, 256, 0, stream>>>(OUT, scaleb, shiftb, slope, Ab,
                                                                    (size_t)N * HD);
  };
  auto cheb_layer = [&](const float* Wk, const float* bk) {
    k_gemm128<<<gb, 256, 0, stream>>>(Ab, Wk, bk, OUT, N, 1);
    k_prop128<<<pb, 256, 0, stream>>>(rowptr, col, wgt, Ab, nullptr, Bb, 1.f, N);
    k_gemm128<<<gb, 256, 0, stream>>>(Bb, Wk + 1 * HD * HD, bk, OUT, N, 0);
    k_prop128<<<pb, 256, 0, stream>>>(rowptr, col, wgt, Bb, Ab, Cb, 2.f, N);
    k_gemm128<<<gb, 256, 0, stream>>>(Cb, Wk + 2 * HD * HD, bk, OUT, N, 0);
    k_prop128<<<pb, 256, 0, stream>>>(rowptr, col, wgt, Cb, Bb, Ab, 2.f, N);
    k_gemm128<<<gb, 256, 0, stream>>>(Ab, Wk + 3 * HD * HD, bk, OUT, N, 0);
  };

  // ---- layer 1 (fi=3) ----
  k_prop3<<<nb, 256, 0, stream>>>(rowptr, col, wgt, x, nullptr, t1, 1.f, N);
  k_prop3<<<nb, 256, 0, stream>>>(rowptr, col, wgt, t1, x, t2, 2.f, N);
  k_prop3<<<nb, 256, 0, stream>>>(rowptr, col, wgt, t2, t1, t3, 2.f, N);
  k_l1gemm<<<((size_t)N * HD + 255) / 256, 256, 0, stream>>>(x, t1, t2, t3, W1, b1, OUT, N);
  bn_act(g1, be1, 0.01f);

  // ---- layers 2..3 ----
  cheb_layer(W2, b2);
  bn_act(g2, be2, 0.01f);
  cheb_layer(W3, b3);
  bn_act(g3, be3, 0.0f);

  // ---- layer 4 (no act/bn) ----
  cheb_layer(W4, b4);

  // ---- L2 normalize + readout ----
  k_final<<<pb, 256, 0, stream>>>(OUT, Wr, br, out, N);
}

// Round 2
// 1165.985 us; speedup vs baseline: 1.1693x; 1.1693x over previous
//
#include <hip/hip_runtime.h>

#define HD 128

__device__ __forceinline__ float lrelu(float x, float s) { return x > 0.f ? x : s * x; }

// ---------------- graph prep ----------------
__global__ void k_edge_count(const int* __restrict__ src, const int* __restrict__ dst,
                             int* __restrict__ degc, int* __restrict__ cnt, int E) {
  int e = blockIdx.x * blockDim.x + threadIdx.x;
  if (e < E) {
    atomicAdd(&degc[src[e]], 1);
    atomicAdd(&cnt[dst[e]], 1);
  }
}

__global__ void k_dinv(const int* __restrict__ degc, float* __restrict__ dinv, int n) {
  int i = blockIdx.x * blockDim.x + threadIdx.x;
  if (i < n) {
    int d = degc[i];
    dinv[i] = d > 0 ? rsqrtf((float)d) : 0.f;
  }
}

// 3-phase scan: per-block local exclusive scan + block sums
__global__ __launch_bounds__(1024) void k_scan1(const int* __restrict__ cnt,
                                                int* __restrict__ rowptr,
                                                int* __restrict__ bsums, int n) {
  __shared__ int buf[1024];
  int i = blockIdx.x * 1024 + threadIdx.x;
  int v = (i < n) ? cnt[i] : 0;
  buf[threadIdx.x] = v;
  __syncthreads();
  for (int o = 1; o < 1024; o <<= 1) {
    int t = (threadIdx.x >= (unsigned)o) ? buf[threadIdx.x - o] : 0;
    __syncthreads();
    buf[threadIdx.x] += t;
    __syncthreads();
  }
  if (i < n) rowptr[i] = buf[threadIdx.x] - v;  // local exclusive
  if (threadIdx.x == 1023) bsums[blockIdx.x] = buf[1023];
}

// scan the (<=64) block sums in one wave, in-place exclusive
__global__ void k_scan2(int* __restrict__ bsums, int nb) {
  int lane = threadIdx.x;
  int orig = (lane < nb) ? bsums[lane] : 0;
  int v = orig;
#pragma unroll
  for (int o = 1; o < 64; o <<= 1) {
    int t = __shfl_up(v, o, 64);
    if (lane >= o) v += t;
  }
  if (lane < nb) bsums[lane] = v - orig;
}

__global__ __launch_bounds__(1024) void k_scan3(int* __restrict__ rowptr, int* __restrict__ wo,
                                                const int* __restrict__ bsums, int n, int Etot) {
  int i = blockIdx.x * 1024 + threadIdx.x;
  if (i < n) {
    int r = rowptr[i] + bsums[blockIdx.x];
    rowptr[i] = r;
    wo[i] = r;
  }
  if (i == 0) rowptr[n] = Etot;
}

__global__ void k_fill(const int* __restrict__ src, const int* __restrict__ dst,
                       int* __restrict__ wo, const float* __restrict__ dinv,
                       int* __restrict__ col, float* __restrict__ wgt, int E) {
  int e = blockIdx.x * blockDim.x + threadIdx.x;
  if (e < E) {
    int s = src[e], d = dst[e];
    int p = atomicAdd(&wo[d], 1);
    col[p] = s;
    wgt[p] = -dinv[s] * dinv[d];
  }
}

// ---------------- props ----------------
__global__ void k_prop3(const int* __restrict__ rowptr, const int* __restrict__ col,
                        const float* __restrict__ wgt, const float* __restrict__ Hs,
                        const float* __restrict__ Sub, float* __restrict__ Out,
                        float scale, int n) {
  int r = blockIdx.x * blockDim.x + threadIdx.x;
  if (r >= n) return;
  int b = rowptr[r], e = rowptr[r + 1];
  float a0 = 0.f, a1 = 0.f, a2 = 0.f;
  for (int j = b; j < e; ++j) {
    int s = col[j];
    float w = wgt[j];
    a0 = fmaf(w, Hs[s * 3 + 0], a0);
    a1 = fmaf(w, Hs[s * 3 + 1], a1);
    a2 = fmaf(w, Hs[s * 3 + 2], a2);
  }
  float r0 = scale * a0, r1 = scale * a1, r2 = scale * a2;
  if (Sub) { r0 -= Sub[r * 3 + 0]; r1 -= Sub[r * 3 + 1]; r2 -= Sub[r * 3 + 2]; }
  Out[r * 3 + 0] = r0; Out[r * 3 + 1] = r1; Out[r * 3 + 2] = r2;
}

// F=128 prop: one wave per dst row, 2 features per lane
__global__ __launch_bounds__(256) void k_prop128(
    const int* __restrict__ rowptr, const int* __restrict__ col,
    const float* __restrict__ wgt, const float* __restrict__ Hs,
    const float* __restrict__ Sub, float* __restrict__ Out, float scale, int n) {
  int r = blockIdx.x * 4 + (int)(threadIdx.x >> 6);
  int lane = threadIdx.x & 63;
  if (r >= n) return;
  int b = rowptr[r], e = rowptr[r + 1];
  float a0 = 0.f, a1 = 0.f;
  int j = b;
  for (; j + 1 < e; j += 2) {
    int s0 = col[j], s1 = col[j + 1];
    float w0 = wgt[j], w1 = wgt[j + 1];
    const float* p0 = Hs + (size_t)s0 * HD;
    const float* p1 = Hs + (size_t)s1 * HD;
    a0 = fmaf(w0, p0[lane], a0);
    a1 = fmaf(w0, p0[64 + lane], a1);
    a0 = fmaf(w1, p1[lane], a0);
    a1 = fmaf(w1, p1[64 + lane], a1);
  }
  if (j < e) {
    int s0 = col[j];
    float w0 = wgt[j];
    const float* p0 = Hs + (size_t)s0 * HD;
    a0 = fmaf(w0, p0[lane], a0);
    a1 = fmaf(w0, p0[64 + lane], a1);
  }
  float r0 = scale * a0, r1 = scale * a1;
  if (Sub) {
    r0 -= Sub[(size_t)r * HD + lane];
    r1 -= Sub[(size_t)r * HD + 64 + lane];
  }
  Out[(size_t)r * HD + lane] = r0;
  Out[(size_t)r * HD + 64 + lane] = r1;
}

// ---------------- layer-1 fused gemm (fi=3, K=4) ----------------
__global__ void k_l1gemm(const float* __restrict__ X, const float* __restrict__ T1,
                         const float* __restrict__ T2, const float* __restrict__ T3,
                         const float* __restrict__ W1, const float* __restrict__ b1,
                         float* __restrict__ Out, int n) {
  int idx = blockIdx.x * blockDim.x + threadIdx.x;
  int r = idx >> 7, j = idx & 127;
  if (r >= n) return;
  float acc = b1[j];
#pragma unroll
  for (int c = 0; c < 3; ++c) {
    acc = fmaf(X [r * 3 + c], W1[0 * 3 * HD + c * HD + j], acc);
    acc = fmaf(T1[r * 3 + c], W1[1 * 3 * HD + c * HD + j], acc);
    acc = fmaf(T2[r * 3 + c], W1[2 * 3 * HD + c * HD + j], acc);
    acc = fmaf(T3[r * 3 + c], W1[3 * 3 * HD + c * HD + j], acc);
  }
  Out[(size_t)r * HD + j] = acc;
}

// ---------------- fused 4-term GEMM ----------------
// OUT[n,128] = bias + T0@W[0] + T1@W[1] + T2@W[2] + T3@W[3]
// optional fused BN stats of act(OUT) via atomics into bnsum/bnsq.
// block: 256 threads; tile 128 rows x 128 cols; per-thread 8x8.
// NOTE: T3 may alias OUT (per-block row ranges: all reads precede writes).
__global__ __launch_bounds__(256) void k_gemm4(
    const float* __restrict__ T0, const float* __restrict__ T1,
    const float* __restrict__ T2, const float* __restrict__ T3,
    const float* __restrict__ W, const float* __restrict__ bias,
    float* __restrict__ OUT, float* bnsum, float* bnsq, float slope, int n) {
  __shared__ float sAT[32][132];  // [k][row], stride 132 -> 16B-aligned b128, conflict-free reads
  __shared__ float sWs[32][128];  // [k][col]
  int tid = threadIdx.x;
  int cg8 = (tid & 15) << 3;   // col start
  int rg  = tid >> 4;          // row group 0..15
  int rg8 = rg << 3;           // row start
  int row0 = blockIdx.x * 128;

  float acc[8][8];
#pragma unroll
  for (int i = 0; i < 8; ++i)
#pragma unroll
    for (int j = 0; j < 8; ++j) acc[i][j] = 0.f;

  for (int t = 0; t < 4; ++t) {
    const float* Tsrc = (t == 0) ? T0 : (t == 1) ? T1 : (t == 2) ? T2 : T3;
    for (int kc = 0; kc < 4; ++kc) {
#pragma unroll
      for (int p = 0; p < 4; ++p) {  // stage A chunk 128x32, transposed into sAT
        int q = tid + p * 256;
        int ar = q >> 3;
        int ac = (q & 7) << 2;
        int gr = row0 + ar;
        float4 v = make_float4(0.f, 0.f, 0.f, 0.f);
        if (gr < n) v = *(const float4*)&Tsrc[(size_t)gr * HD + kc * 32 + ac];
        sAT[ac + 0][ar] = v.x;
        sAT[ac + 1][ar] = v.y;
        sAT[ac + 2][ar] = v.z;
        sAT[ac + 3][ar] = v.w;
      }
#pragma unroll
      for (int p = 0; p < 4; ++p) {  // stage W chunk 32x128
        int q = tid + p * 256;
        int wr = q >> 5;
        int wc = (q & 31) << 2;
        *(float4*)&sWs[wr][wc] =
            *(const float4*)&W[(size_t)(t * HD + kc * 32 + wr) * HD + wc];
      }
      __syncthreads();
#pragma unroll 4
      for (int k = 0; k < 32; ++k) {
        float4 av0 = *(const float4*)&sAT[k][rg8];
        float4 av1 = *(const float4*)&sAT[k][rg8 + 4];
        float4 wv0 = *(const float4*)&sWs[k][cg8];
        float4 wv1 = *(const float4*)&sWs[k][cg8 + 4];
        float a8[8] = {av0.x, av0.y, av0.z, av0.w, av1.x, av1.y, av1.z, av1.w};
        float w8[8] = {wv0.x, wv0.y, wv0.z, wv0.w, wv1.x, wv1.y, wv1.z, wv1.w};
#pragma unroll
        for (int i = 0; i < 8; ++i)
#pragma unroll
          for (int j = 0; j < 8; ++j) acc[i][j] = fmaf(a8[i], w8[j], acc[i][j]);
      }
      __syncthreads();
    }
  }

  // epilogue: bias, write, optional BN stats
  float cs[8], cq[8];
#pragma unroll
  for (int j = 0; j < 8; ++j) { cs[j] = 0.f; cq[j] = 0.f; }
  float bj[8];
#pragma unroll
  for (int j = 0; j < 8; ++j) bj[j] = bias[cg8 + j];

#pragma unroll
  for (int i = 0; i < 8; ++i) {
    int gr = row0 + rg8 + i;
    if (gr < n) {
      float o[8];
#pragma unroll
      for (int j = 0; j < 8; ++j) o[j] = acc[i][j] + bj[j];
      float4 w0 = make_float4(o[0], o[1], o[2], o[3]);
      float4 w1 = make_float4(o[4], o[5], o[6], o[7]);
      float* dp = &OUT[(size_t)gr * HD + cg8];
      *(float4*)dp = w0;
      *(float4*)(dp + 4) = w1;
      if (bnsum) {
#pragma unroll
        for (int j = 0; j < 8; ++j) {
          float v = lrelu(o[j], slope);
          cs[j] += v;
          cq[j] = fmaf(v, v, cq[j]);
        }
      }
    }
  }

  if (bnsum) {
    float* redA = &sWs[0][0];  // 16x128
    float* redB = &sAT[0][0];  // 16x128 (fits in 32x132)
#pragma unroll
    for (int j = 0; j < 8; ++j) {
      redA[rg * 128 + cg8 + j] = cs[j];
      redB[rg * 128 + cg8 + j] = cq[j];
    }
    __syncthreads();
    if (tid < 128) {
      float s = 0.f, q = 0.f;
#pragma unroll
      for (int g = 0; g < 16; ++g) {
        s += redA[g * 128 + tid];
        q += redB[g * 128 + tid];
      }
      atomicAdd(&bnsum[tid], s);
      atomicAdd(&bnsq[tid], q);
    }
  }
}

// ---------------- batchnorm (stats kernel used for layer 1 only) ----------------
__global__ __launch_bounds__(256) void k_bnstat(const float* __restrict__ Hb, float slope,
                                                float* __restrict__ bsum, float* __restrict__ bsq,
                                                int n) {
  int f = threadIdx.x & 127;
  int h = threadIdx.x >> 7;
  float s = 0.f, s2 = 0.f;
  for (int r = blockIdx.x * 2 + h; r < n; r += gridDim.x * 2) {
    float v = lrelu(Hb[(size_t)r * HD + f], slope);
    s += v;
    s2 = fmaf(v, v, s2);
  }
  __shared__ float ls[256], ls2[256];
  ls[threadIdx.x] = s; ls2[threadIdx.x] = s2;
  __syncthreads();
  if (threadIdx.x < 128) {
    atomicAdd(&bsum[f], ls[threadIdx.x] + ls[threadIdx.x + 128]);
    atomicAdd(&bsq[f], ls2[threadIdx.x] + ls2[threadIdx.x + 128]);
  }
}

__global__ void k_bnfin(const float* __restrict__ bsum, const float* __restrict__ bsq,
                        const float* __restrict__ g, const float* __restrict__ be,
                        float* __restrict__ scaleb, float* __restrict__ shiftb, int n) {
  int f = threadIdx.x;
  if (f < HD) {
    float m = bsum[f] / (float)n;
    float v = bsq[f] / (float)n - m * m;
    float rs = rsqrtf(v + 1e-5f);
    float sc = g[f] * rs;
    scaleb[f] = sc;
    shiftb[f] = be[f] - m * sc;
  }
}

__global__ void k_bnapply(const float* __restrict__ In, const float* __restrict__ scaleb,
                          const float* __restrict__ shiftb, float slope,
                          float* __restrict__ Outb, size_t total) {
  size_t i = (size_t)(blockIdx.x * blockDim.x + threadIdx.x) * 4;
  if (i >= total) return;
  float4 v = *(const float4*)&In[i];
  int f = (int)(i & 127);
  float4 o;
  o.x = fmaf(lrelu(v.x, slope), scaleb[f + 0], shiftb[f + 0]);
  o.y = fmaf(lrelu(v.y, slope), scaleb[f + 1], shiftb[f + 1]);
  o.z = fmaf(lrelu(v.z, slope), scaleb[f + 2], shiftb[f + 2]);
  o.w = fmaf(lrelu(v.w, slope), scaleb[f + 3], shiftb[f + 3]);
  *(float4*)&Outb[i] = o;
}

// ---------------- final: row L2-normalize + @Wr + br ----------------
__global__ __launch_bounds__(256) void k_final(const float* __restrict__ Hb,
                                               const float* __restrict__ Wr,
                                               const float* __restrict__ br,
                                               float* __restrict__ out, int n) {
  int r = blockIdx.x * 4 + (int)(threadIdx.x >> 6);
  int lane = threadIdx.x & 63;
  if (r >= n) return;
  float h0 = Hb[(size_t)r * HD + lane];
  float h1 = Hb[(size_t)r * HD + 64 + lane];
  float ss = h0 * h0 + h1 * h1;
#pragma unroll
  for (int o = 32; o; o >>= 1) ss += __shfl_xor(ss, o, 64);
  float inv = 1.f / fmaxf(sqrtf(ss), 1e-12f);
  h0 *= inv; h1 *= inv;
  float o0 = h0 * Wr[lane * 3 + 0] + h1 * Wr[(64 + lane) * 3 + 0];
  float o1 = h0 * Wr[lane * 3 + 1] + h1 * Wr[(64 + lane) * 3 + 1];
  float o2 = h0 * Wr[lane * 3 + 2] + h1 * Wr[(64 + lane) * 3 + 2];
#pragma unroll
  for (int o = 32; o; o >>= 1) {
    o0 += __shfl_xor(o0, o, 64);
    o1 += __shfl_xor(o1, o, 64);
    o2 += __shfl_xor(o2, o, 64);
  }
  if (lane == 0) {
    out[r * 3 + 0] = o0 + br[0];
    out[r * 3 + 1] = o1 + br[1];
    out[r * 3 + 2] = o2 + br[2];
  }
}

extern "C" void kernel_launch(void* const* d_in, const int* in_sizes, int n_in,
                              void* d_out, int out_size, void* d_ws, size_t ws_size,
                              hipStream_t stream) {
  const float* x  = (const float*)d_in[0];
  const int*   ei = (const int*)d_in[1];
  const float* W1 = (const float*)d_in[2];
  const float* b1 = (const float*)d_in[3];
  const float* W2 = (const float*)d_in[4];
  const float* b2 = (const float*)d_in[5];
  const float* W3 = (const float*)d_in[6];
  const float* b3 = (const float*)d_in[7];
  const float* W4 = (const float*)d_in[8];
  const float* b4 = (const float*)d_in[9];
  const float* g1 = (const float*)d_in[10];
  const float* be1= (const float*)d_in[11];
  const float* g2 = (const float*)d_in[12];
  const float* be2= (const float*)d_in[13];
  const float* g3 = (const float*)d_in[14];
  const float* be3= (const float*)d_in[15];
  const float* Wr = (const float*)d_in[16];
  const float* br = (const float*)d_in[17];

  const int N = in_sizes[0] / 3;
  const int E = in_sizes[1] / 2;
  const int* src = ei;
  const int* dst = ei + E;
  float* out = (float*)d_out;

  char* wp = (char*)d_ws;
  size_t used = 0;
  auto alloc = [&](size_t bytes) -> void* {
    void* p = (void*)(wp + used);
    used += (bytes + 255) & ~(size_t)255;
    return p;
  };
  int*   degc   = (int*)alloc((size_t)N * 4);
  int*   cnt    = (int*)alloc((size_t)N * 4);
  int*   rowptr = (int*)alloc((size_t)(N + 1) * 4);
  int*   wo     = (int*)alloc((size_t)N * 4);
  float* dinv   = (float*)alloc((size_t)N * 4);
  int*   bsums  = (int*)alloc(256 * 4);
  int*   col    = (int*)alloc((size_t)E * 4);
  float* wgt    = (float*)alloc((size_t)E * 4);
  float* t1     = (float*)alloc((size_t)N * 3 * 4);
  float* t2     = (float*)alloc((size_t)N * 3 * 4);
  float* t3     = (float*)alloc((size_t)N * 3 * 4);
  float* Ab     = (float*)alloc((size_t)N * HD * 4);
  float* Bb     = (float*)alloc((size_t)N * HD * 4);
  float* Cb     = (float*)alloc((size_t)N * HD * 4);
  float* OUT    = (float*)alloc((size_t)N * HD * 4);
  float* bnsum  = (float*)alloc(HD * 4);
  float* bnsq   = (float*)alloc(HD * 4);
  float* scaleb = (float*)alloc(HD * 4);
  float* shiftb = (float*)alloc(HD * 4);
  if (used > ws_size) return;

  const int eb = (E + 255) / 256;
  const int nb = (N + 255) / 256;
  const int pb = (N + 3) / 4;
  const int sb = (N + 1023) / 1024;
  const int gb4 = (N + 127) / 128;

  hipMemsetAsync(degc, 0, (size_t)N * 4, stream);
  hipMemsetAsync(cnt, 0, (size_t)N * 4, stream);
  k_edge_count<<<eb, 256, 0, stream>>>(src, dst, degc, cnt, E);
  k_dinv<<<nb, 256, 0, stream>>>(degc, dinv, N);
  k_scan1<<<sb, 1024, 0, stream>>>(cnt, rowptr, bsums, N);
  k_scan2<<<1, 64, 0, stream>>>(bsums, sb);
  k_scan3<<<sb, 1024, 0, stream>>>(rowptr, wo, bsums, N, E);
  k_fill<<<eb, 256, 0, stream>>>(src, dst, wo, dinv, col, wgt, E);

  auto bn_fin_apply = [&](const float* g, const float* be, float slope) {
    k_bnfin<<<1, 128, 0, stream>>>(bnsum, bnsq, g, be, scaleb, shiftb, N);
    k_bnapply<<<((size_t)N * HD / 4 + 255) / 256, 256, 0, stream>>>(OUT, scaleb, shiftb, slope, Ab,
                                                                    (size_t)N * HD);
  };

  // ---- layer 1 (fi=3) ----
  k_prop3<<<nb, 256, 0, stream>>>(rowptr, col, wgt, x, nullptr, t1, 1.f, N);
  k_prop3<<<nb, 256, 0, stream>>>(rowptr, col, wgt, t1, x, t2, 2.f, N);
  k_prop3<<<nb, 256, 0, stream>>>(rowptr, col, wgt, t2, t1, t3, 2.f, N);
  k_l1gemm<<<((size_t)N * HD + 255) / 256, 256, 0, stream>>>(x, t1, t2, t3, W1, b1, OUT, N);
  hipMemsetAsync(bnsum, 0, HD * 4, stream);
  hipMemsetAsync(bnsq, 0, HD * 4, stream);
  k_bnstat<<<256, 256, 0, stream>>>(OUT, 0.01f, bnsum, bnsq, N);
  bn_fin_apply(g1, be1, 0.01f);

  // ---- layers 2..4 ----
  auto cheb_layer = [&](const float* Wk, const float* bk, bool stats, float slope) {
    k_prop128<<<pb, 256, 0, stream>>>(rowptr, col, wgt, Ab, nullptr, Bb, 1.f, N);
    k_prop128<<<pb, 256, 0, stream>>>(rowptr, col, wgt, Bb, Ab, Cb, 2.f, N);
    k_prop128<<<pb, 256, 0, stream>>>(rowptr, col, wgt, Cb, Bb, OUT, 2.f, N);  // T3 -> OUT
    if (stats) {
      hipMemsetAsync(bnsum, 0, HD * 4, stream);
      hipMemsetAsync(bnsq, 0, HD * 4, stream);
    }
    k_gemm4<<<gb4, 256, 0, stream>>>(Ab, Bb, Cb, OUT, Wk, bk, OUT,
                                     stats ? bnsum : nullptr, stats ? bnsq : nullptr, slope, N);
  };

  cheb_layer(W2, b2, true, 0.01f);
  bn_fin_apply(g2, be2, 0.01f);
  cheb_layer(W3, b3, true, 0.0f);
  bn_fin_apply(g3, be3, 0.0f);
  cheb_layer(W4, b4, false, 0.0f);

  // ---- L2 normalize + readout ----
  k_final<<<pb, 256, 0, stream>>>(OUT, Wr, br, out, N);
}

// Round 3
// 962.696 us; speedup vs baseline: 1.4162x; 1.2112x over previous
//
#include <hip/hip_runtime.h>

#define HD 128

typedef __attribute__((ext_vector_type(8))) short bf16x8;
typedef __attribute__((ext_vector_type(4))) float f32x4;
typedef unsigned int u32;

__device__ __forceinline__ float lrelu(float x, float s) { return x > 0.f ? x : s * x; }

__device__ __forceinline__ u32 bf16rtne(float x) {
  u32 u = __float_as_uint(x);
  return (u + 0x7fffu + ((u >> 16) & 1u)) >> 16;
}

// ---------------- graph prep ----------------
__global__ void k_edge_count(const int* __restrict__ src, const int* __restrict__ dst,
                             int* __restrict__ degc, int* __restrict__ cnt, int E) {
  int e = blockIdx.x * blockDim.x + threadIdx.x;
  if (e < E) {
    atomicAdd(&degc[src[e]], 1);
    atomicAdd(&cnt[dst[e]], 1);
  }
}

__global__ void k_dinv(const int* __restrict__ degc, float* __restrict__ dinv, int n) {
  int i = blockIdx.x * blockDim.x + threadIdx.x;
  if (i < n) {
    int d = degc[i];
    dinv[i] = d > 0 ? rsqrtf((float)d) : 0.f;
  }
}

__global__ __launch_bounds__(1024) void k_scan1(const int* __restrict__ cnt,
                                                int* __restrict__ rowptr,
                                                int* __restrict__ bsums, int n) {
  __shared__ int buf[1024];
  int i = blockIdx.x * 1024 + threadIdx.x;
  int v = (i < n) ? cnt[i] : 0;
  buf[threadIdx.x] = v;
  __syncthreads();
  for (int o = 1; o < 1024; o <<= 1) {
    int t = (threadIdx.x >= (unsigned)o) ? buf[threadIdx.x - o] : 0;
    __syncthreads();
    buf[threadIdx.x] += t;
    __syncthreads();
  }
  if (i < n) rowptr[i] = buf[threadIdx.x] - v;
  if (threadIdx.x == 1023) bsums[blockIdx.x] = buf[1023];
}

__global__ void k_scan2(int* __restrict__ bsums, int nb) {
  int lane = threadIdx.x;
  int orig = (lane < nb) ? bsums[lane] : 0;
  int v = orig;
#pragma unroll
  for (int o = 1; o < 64; o <<= 1) {
    int t = __shfl_up(v, o, 64);
    if (lane >= o) v += t;
  }
  if (lane < nb) bsums[lane] = v - orig;
}

__global__ __launch_bounds__(1024) void k_scan3(int* __restrict__ rowptr, int* __restrict__ wo,
                                                const int* __restrict__ bsums, int n, int Etot) {
  int i = blockIdx.x * 1024 + threadIdx.x;
  if (i < n) {
    int r = rowptr[i] + bsums[blockIdx.x];
    rowptr[i] = r;
    wo[i] = r;
  }
  if (i == 0) rowptr[n] = Etot;
}

__global__ void k_fill(const int* __restrict__ src, const int* __restrict__ dst,
                       int* __restrict__ wo, const float* __restrict__ dinv,
                       int* __restrict__ col, float* __restrict__ wgt, int E) {
  int e = blockIdx.x * blockDim.x + threadIdx.x;
  if (e < E) {
    int s = src[e], d = dst[e];
    int p = atomicAdd(&wo[d], 1);
    col[p] = s;
    wgt[p] = -dinv[s] * dinv[d];
  }
}

// ---------------- props ----------------
__global__ void k_prop3(const int* __restrict__ rowptr, const int* __restrict__ col,
                        const float* __restrict__ wgt, const float* __restrict__ Hs,
                        const float* __restrict__ Sub, float* __restrict__ Out,
                        float scale, int n) {
  int r = blockIdx.x * blockDim.x + threadIdx.x;
  if (r >= n) return;
  int b = rowptr[r], e = rowptr[r + 1];
  float a0 = 0.f, a1 = 0.f, a2 = 0.f;
  for (int j = b; j < e; ++j) {
    int s = col[j];
    float w = wgt[j];
    a0 = fmaf(w, Hs[s * 3 + 0], a0);
    a1 = fmaf(w, Hs[s * 3 + 1], a1);
    a2 = fmaf(w, Hs[s * 3 + 2], a2);
  }
  float r0 = scale * a0, r1 = scale * a1, r2 = scale * a2;
  if (Sub) { r0 -= Sub[r * 3 + 0]; r1 -= Sub[r * 3 + 1]; r2 -= Sub[r * 3 + 2]; }
  Out[r * 3 + 0] = r0; Out[r * 3 + 1] = r1; Out[r * 3 + 2] = r2;
}

// F=128 prop: one wave per dst row, float2 (features 2*lane, 2*lane+1) per lane
__global__ __launch_bounds__(256) void k_prop128(
    const int* __restrict__ rowptr, const int* __restrict__ col,
    const float* __restrict__ wgt, const float* __restrict__ Hs,
    const float* __restrict__ Sub, float* __restrict__ Out, float scale, int n) {
  int r = blockIdx.x * 4 + (int)(threadIdx.x >> 6);
  int lane = threadIdx.x & 63;
  if (r >= n) return;
  int b = rowptr[r], e = rowptr[r + 1];
  float a0x = 0.f, a0y = 0.f, a1x = 0.f, a1y = 0.f;
  int j = b;
  for (; j + 3 < e; j += 4) {
    int s0 = col[j], s1 = col[j + 1], s2 = col[j + 2], s3 = col[j + 3];
    float w0 = wgt[j], w1 = wgt[j + 1], w2 = wgt[j + 2], w3 = wgt[j + 3];
    float2 h0 = *(const float2*)&Hs[(size_t)s0 * HD + 2 * lane];
    float2 h1 = *(const float2*)&Hs[(size_t)s1 * HD + 2 * lane];
    float2 h2 = *(const float2*)&Hs[(size_t)s2 * HD + 2 * lane];
    float2 h3 = *(const float2*)&Hs[(size_t)s3 * HD + 2 * lane];
    a0x = fmaf(w0, h0.x, a0x); a0y = fmaf(w0, h0.y, a0y);
    a1x = fmaf(w1, h1.x, a1x); a1y = fmaf(w1, h1.y, a1y);
    a0x = fmaf(w2, h2.x, a0x); a0y = fmaf(w2, h2.y, a0y);
    a1x = fmaf(w3, h3.x, a1x); a1y = fmaf(w3, h3.y, a1y);
  }
  for (; j < e; ++j) {
    int s0 = col[j];
    float w0 = wgt[j];
    float2 h0 = *(const float2*)&Hs[(size_t)s0 * HD + 2 * lane];
    a0x = fmaf(w0, h0.x, a0x); a0y = fmaf(w0, h0.y, a0y);
  }
  float rx = scale * (a0x + a1x), ry = scale * (a0y + a1y);
  if (Sub) {
    float2 sb = *(const float2*)&Sub[(size_t)r * HD + 2 * lane];
    rx -= sb.x; ry -= sb.y;
  }
  float2 o = make_float2(rx, ry);
  *(float2*)&Out[(size_t)r * HD + 2 * lane] = o;
}

// ---------------- layer-1 fused gemm (fi=3, K=4) ----------------
__global__ void k_l1gemm(const float* __restrict__ X, const float* __restrict__ T1,
                         const float* __restrict__ T2, const float* __restrict__ T3,
                         const float* __restrict__ W1, const float* __restrict__ b1,
                         float* __restrict__ Out, int n) {
  int idx = blockIdx.x * blockDim.x + threadIdx.x;
  int r = idx >> 7, j = idx & 127;
  if (r >= n) return;
  float acc = b1[j];
#pragma unroll
  for (int c = 0; c < 3; ++c) {
    acc = fmaf(X [r * 3 + c], W1[0 * 3 * HD + c * HD + j], acc);
    acc = fmaf(T1[r * 3 + c], W1[1 * 3 * HD + c * HD + j], acc);
    acc = fmaf(T2[r * 3 + c], W1[2 * 3 * HD + c * HD + j], acc);
    acc = fmaf(T3[r * 3 + c], W1[3 * 3 * HD + c * HD + j], acc);
  }
  Out[(size_t)r * HD + j] = acc;
}

// ---------------- W pre-split: fp32 [512][128] -> hi/lo bf16 in MFMA frag-slot order ----
// slot = chunk*512 + (n>>4)*64 + g*16 + (n&15); payload k = chunk*32 + (i>>2)*16 + g*4 + (i&3)
__global__ void k_wsplit(const float* __restrict__ W, uint4* __restrict__ Whi,
                         uint4* __restrict__ Wlo) {
  int flat = blockIdx.x * 256 + threadIdx.x;  // 8192 threads total
  int n = flat & 127, K8 = flat >> 7;         // K8: 0..63
  int chunk = K8 >> 2, g = K8 & 3;
  bf16x8 hv, lv;
#pragma unroll
  for (int i = 0; i < 8; ++i) {
    int k = chunk * 32 + ((i >> 2) << 4) + g * 4 + (i & 3);
    float v = W[(size_t)k * HD + n];
    u32 hb = bf16rtne(v);
    float hf = __uint_as_float(hb << 16);
    u32 lb = bf16rtne(v - hf);
    hv[i] = (short)hb;
    lv[i] = (short)lb;
  }
  int slot = chunk * 512 + (n >> 4) * 64 + g * 16 + (n & 15);
  Whi[slot] = *(uint4*)&hv;
  Wlo[slot] = *(uint4*)&lv;
}

// ---------------- fused 4-term GEMM via bf16x3 MFMA ----------------
// OUT[n,128] = bias + T0@W[0..127] + T1@W[128..255] + T2@W[..] + T3@W[..]
// BM=64, BN=128, 4 waves; wave (wr,wc) owns 32 rows x 64 cols (2 m-frags x 4 n-frags).
// T3 may alias OUT (all reads of a block's rows precede its writes).
__global__ __launch_bounds__(256) void k_gemm4m(
    const float* __restrict__ T0, const float* __restrict__ T1,
    const float* __restrict__ T2, const float* __restrict__ T3,
    const uint4* __restrict__ Whi, const uint4* __restrict__ Wlo,
    const float* __restrict__ bias, float* __restrict__ OUT,
    float* bnsum, float* bnsq, float slope, int nrows) {
  __shared__ short sAh[2048], sAl[2048];  // 256 slots x 8 bf16 (linear, conflict-free)
  __shared__ short sWh[4096], sWl[4096];  // 512 slots x 8 bf16
  __shared__ float redS[128], redQ[128];

  int tid = threadIdx.x;
  int lane = tid & 63, w = tid >> 6, wr = w >> 1, wc = w & 1;
  int g = (tid >> 4) & 3, ri = tid & 15;  // A-staging coords (m = w)
  int row0 = blockIdx.x * 64;
  int arow = row0 + w * 16 + ri;
  bool aval = arow < nrows;

  f32x4 zero = {0.f, 0.f, 0.f, 0.f};
  f32x4 acc[2][4];
#pragma unroll
  for (int mi = 0; mi < 2; ++mi)
#pragma unroll
    for (int nj = 0; nj < 4; ++nj) acc[mi][nj] = zero;

  if (tid < 128) { redS[tid] = 0.f; redQ[tid] = 0.f; }

  for (int chunk = 0; chunk < 16; ++chunk) {
    const float* Ts = (chunk < 4) ? T0 : (chunk < 8) ? T1 : (chunk < 12) ? T2 : T3;
    int kc = chunk & 3;
    // issue global loads early (overlap prior compute)
    float4 va = make_float4(0.f, 0.f, 0.f, 0.f), vb = va;
    if (aval) {
      const float* ap = Ts + (size_t)arow * HD + kc * 32 + g * 4;
      va = *(const float4*)ap;
      vb = *(const float4*)(ap + 16);
    }
    size_t wbase = (size_t)chunk * 512;
    uint4 wh0 = Whi[wbase + tid], wh1 = Whi[wbase + 256 + tid];
    uint4 wl0 = Wlo[wbase + tid], wl1 = Wlo[wbase + 256 + tid];

    __syncthreads();  // previous chunk's LDS reads done

    float vals[8] = {va.x, va.y, va.z, va.w, vb.x, vb.y, vb.z, vb.w};
    bf16x8 hv, lv;
#pragma unroll
    for (int i = 0; i < 8; ++i) {
      u32 hb = bf16rtne(vals[i]);
      float hf = __uint_as_float(hb << 16);
      u32 lb = bf16rtne(vals[i] - hf);
      hv[i] = (short)hb;
      lv[i] = (short)lb;
    }
    *(bf16x8*)&sAh[tid * 8] = hv;
    *(bf16x8*)&sAl[tid * 8] = lv;
    *(uint4*)&sWh[tid * 8] = wh0;
    *(uint4*)&sWh[(256 + tid) * 8] = wh1;
    *(uint4*)&sWl[tid * 8] = wl0;
    *(uint4*)&sWl[(256 + tid) * 8] = wl1;
    __syncthreads();

    bf16x8 ah[2], al[2], bh[4], bl[4];
#pragma unroll
    for (int mi = 0; mi < 2; ++mi) {
      ah[mi] = *(const bf16x8*)&sAh[((wr * 2 + mi) * 64 + lane) * 8];
      al[mi] = *(const bf16x8*)&sAl[((wr * 2 + mi) * 64 + lane) * 8];
    }
#pragma unroll
    for (int nj = 0; nj < 4; ++nj) {
      bh[nj] = *(const bf16x8*)&sWh[((wc * 4 + nj) * 64 + lane) * 8];
      bl[nj] = *(const bf16x8*)&sWl[((wc * 4 + nj) * 64 + lane) * 8];
    }
#pragma unroll
    for (int mi = 0; mi < 2; ++mi)
#pragma unroll
      for (int nj = 0; nj < 4; ++nj) {
        acc[mi][nj] = __builtin_amdgcn_mfma_f32_16x16x32_bf16(ah[mi], bh[nj], acc[mi][nj], 0, 0, 0);
        acc[mi][nj] = __builtin_amdgcn_mfma_f32_16x16x32_bf16(ah[mi], bl[nj], acc[mi][nj], 0, 0, 0);
        acc[mi][nj] = __builtin_amdgcn_mfma_f32_16x16x32_bf16(al[mi], bh[nj], acc[mi][nj], 0, 0, 0);
      }
  }

  // epilogue: bias, store, fused BN stats
  int l4 = (lane >> 4) * 4, ni = lane & 15;
  bool stats = (bnsum != nullptr);
#pragma unroll
  for (int nj = 0; nj < 4; ++nj) {
    int c = wc * 64 + nj * 16 + ni;
    float bcol = bias[c];
    float s = 0.f, q = 0.f;
#pragma unroll
    for (int mi = 0; mi < 2; ++mi)
#pragma unroll
      for (int j = 0; j < 4; ++j) {
        int row = row0 + (wr * 2 + mi) * 16 + l4 + j;
        if (row < nrows) {
          float v = acc[mi][nj][j] + bcol;
          OUT[(size_t)row * HD + c] = v;
          if (stats) {
            float a = lrelu(v, slope);
            s += a;
            q = fmaf(a, a, q);
          }
        }
      }
    if (stats) {
      s += __shfl_xor(s, 16, 64);
      s += __shfl_xor(s, 32, 64);
      q += __shfl_xor(q, 16, 64);
      q += __shfl_xor(q, 32, 64);
      if (lane < 16) {
        atomicAdd(&redS[c], s);
        atomicAdd(&redQ[c], q);
      }
    }
  }
  if (stats) {
    __syncthreads();
    if (tid < 128) {
      atomicAdd(&bnsum[tid], redS[tid]);
      atomicAdd(&bnsq[tid], redQ[tid]);
    }
  }
}

// ---------------- batchnorm ----------------
__global__ __launch_bounds__(256) void k_bnstat(const float* __restrict__ Hb, float slope,
                                                float* __restrict__ bsum, float* __restrict__ bsq,
                                                int n) {
  int f = threadIdx.x & 127;
  int h = threadIdx.x >> 7;
  float s = 0.f, s2 = 0.f;
  for (int r = blockIdx.x * 2 + h; r < n; r += gridDim.x * 2) {
    float v = lrelu(Hb[(size_t)r * HD + f], slope);
    s += v;
    s2 = fmaf(v, v, s2);
  }
  __shared__ float ls[256], ls2[256];
  ls[threadIdx.x] = s; ls2[threadIdx.x] = s2;
  __syncthreads();
  if (threadIdx.x < 128) {
    atomicAdd(&bsum[f], ls[threadIdx.x] + ls[threadIdx.x + 128]);
    atomicAdd(&bsq[f], ls2[threadIdx.x] + ls2[threadIdx.x + 128]);
  }
}

__global__ void k_bnfin(const float* __restrict__ bsum, const float* __restrict__ bsq,
                        const float* __restrict__ g, const float* __restrict__ be,
                        float* __restrict__ scaleb, float* __restrict__ shiftb, int n) {
  int f = threadIdx.x;
  if (f < HD) {
    float m = bsum[f] / (float)n;
    float v = bsq[f] / (float)n - m * m;
    float rs = rsqrtf(v + 1e-5f);
    float sc = g[f] * rs;
    scaleb[f] = sc;
    shiftb[f] = be[f] - m * sc;
  }
}

__global__ void k_bnapply(const float* __restrict__ In, const float* __restrict__ scaleb,
                          const float* __restrict__ shiftb, float slope,
                          float* __restrict__ Outb, size_t total) {
  size_t i = (size_t)(blockIdx.x * blockDim.x + threadIdx.x) * 4;
  if (i >= total) return;
  float4 v = *(const float4*)&In[i];
  int f = (int)(i & 127);
  float4 o;
  o.x = fmaf(lrelu(v.x, slope), scaleb[f + 0], shiftb[f + 0]);
  o.y = fmaf(lrelu(v.y, slope), scaleb[f + 1], shiftb[f + 1]);
  o.z = fmaf(lrelu(v.z, slope), scaleb[f + 2], shiftb[f + 2]);
  o.w = fmaf(lrelu(v.w, slope), scaleb[f + 3], shiftb[f + 3]);
  *(float4*)&Outb[i] = o;
}

// ---------------- final: row L2-normalize + @Wr + br ----------------
__global__ __launch_bounds__(256) void k_final(const float* __restrict__ Hb,
                                               const float* __restrict__ Wr,
                                               const float* __restrict__ br,
                                               float* __restrict__ out, int n) {
  int r = blockIdx.x * 4 + (int)(threadIdx.x >> 6);
  int lane = threadIdx.x & 63;
  if (r >= n) return;
  float h0 = Hb[(size_t)r * HD + lane];
  float h1 = Hb[(size_t)r * HD + 64 + lane];
  float ss = h0 * h0 + h1 * h1;
#pragma unroll
  for (int o = 32; o; o >>= 1) ss += __shfl_xor(ss, o, 64);
  float inv = 1.f / fmaxf(sqrtf(ss), 1e-12f);
  h0 *= inv; h1 *= inv;
  float o0 = h0 * Wr[lane * 3 + 0] + h1 * Wr[(64 + lane) * 3 + 0];
  float o1 = h0 * Wr[lane * 3 + 1] + h1 * Wr[(64 + lane) * 3 + 1];
  float o2 = h0 * Wr[lane * 3 + 2] + h1 * Wr[(64 + lane) * 3 + 2];
#pragma unroll
  for (int o = 32; o; o >>= 1) {
    o0 += __shfl_xor(o0, o, 64);
    o1 += __shfl_xor(o1, o, 64);
    o2 += __shfl_xor(o2, o, 64);
  }
  if (lane == 0) {
    out[r * 3 + 0] = o0 + br[0];
    out[r * 3 + 1] = o1 + br[1];
    out[r * 3 + 2] = o2 + br[2];
  }
}

extern "C" void kernel_launch(void* const* d_in, const int* in_sizes, int n_in,
                              void* d_out, int out_size, void* d_ws, size_t ws_size,
                              hipStream_t stream) {
  const float* x  = (const float*)d_in[0];
  const int*   ei = (const int*)d_in[1];
  const float* W1 = (const float*)d_in[2];
  const float* b1 = (const float*)d_in[3];
  const float* W2 = (const float*)d_in[4];
  const float* b2 = (const float*)d_in[5];
  const float* W3 = (const float*)d_in[6];
  const float* b3 = (const float*)d_in[7];
  const float* W4 = (const float*)d_in[8];
  const float* b4 = (const float*)d_in[9];
  const float* g1 = (const float*)d_in[10];
  const float* be1= (const float*)d_in[11];
  const float* g2 = (const float*)d_in[12];
  const float* be2= (const float*)d_in[13];
  const float* g3 = (const float*)d_in[14];
  const float* be3= (const float*)d_in[15];
  const float* Wr = (const float*)d_in[16];
  const float* br = (const float*)d_in[17];

  const int N = in_sizes[0] / 3;
  const int E = in_sizes[1] / 2;
  const int* src = ei;
  const int* dst = ei + E;
  float* out = (float*)d_out;

  char* wp = (char*)d_ws;
  size_t used = 0;
  auto alloc = [&](size_t bytes) -> void* {
    void* p = (void*)(wp + used);
    used += (bytes + 255) & ~(size_t)255;
    return p;
  };
  int*   degc   = (int*)alloc((size_t)N * 4);
  int*   cnt    = (int*)alloc((size_t)N * 4);
  int*   rowptr = (int*)alloc((size_t)(N + 1) * 4);
  int*   wo     = (int*)alloc((size_t)N * 4);
  float* dinv   = (float*)alloc((size_t)N * 4);
  int*   bsums  = (int*)alloc(256 * 4);
  int*   col    = (int*)alloc((size_t)E * 4);
  float* wgt    = (float*)alloc((size_t)E * 4);
  float* t1     = (float*)alloc((size_t)N * 3 * 4);
  float* t2     = (float*)alloc((size_t)N * 3 * 4);
  float* t3     = (float*)alloc((size_t)N * 3 * 4);
  float* Ab     = (float*)alloc((size_t)N * HD * 4);
  float* Bb     = (float*)alloc((size_t)N * HD * 4);
  float* Cb     = (float*)alloc((size_t)N * HD * 4);
  float* OUT    = (float*)alloc((size_t)N * HD * 4);
  float* bnsum  = (float*)alloc(HD * 4);
  float* bnsq   = (float*)alloc(HD * 4);
  float* scaleb = (float*)alloc(HD * 4);
  float* shiftb = (float*)alloc(HD * 4);
  // pre-split W (hi/lo bf16, frag-slot order): 128KB per array
  uint4* W2hi = (uint4*)alloc(512 * 128 * 2);
  uint4* W2lo = (uint4*)alloc(512 * 128 * 2);
  uint4* W3hi = (uint4*)alloc(512 * 128 * 2);
  uint4* W3lo = (uint4*)alloc(512 * 128 * 2);
  uint4* W4hi = (uint4*)alloc(512 * 128 * 2);
  uint4* W4lo = (uint4*)alloc(512 * 128 * 2);
  if (used > ws_size) return;

  const int eb = (E + 255) / 256;
  const int nb = (N + 255) / 256;
  const int pb = (N + 3) / 4;
  const int sb = (N + 1023) / 1024;
  const int gbm = (N + 63) / 64;

  // graph prep + W pre-split
  hipMemsetAsync(degc, 0, (size_t)N * 4, stream);
  hipMemsetAsync(cnt, 0, (size_t)N * 4, stream);
  k_edge_count<<<eb, 256, 0, stream>>>(src, dst, degc, cnt, E);
  k_dinv<<<nb, 256, 0, stream>>>(degc, dinv, N);
  k_scan1<<<sb, 1024, 0, stream>>>(cnt, rowptr, bsums, N);
  k_scan2<<<1, 64, 0, stream>>>(bsums, sb);
  k_scan3<<<sb, 1024, 0, stream>>>(rowptr, wo, bsums, N, E);
  k_fill<<<eb, 256, 0, stream>>>(src, dst, wo, dinv, col, wgt, E);
  k_wsplit<<<32, 256, 0, stream>>>(W2, W2hi, W2lo);
  k_wsplit<<<32, 256, 0, stream>>>(W3, W3hi, W3lo);
  k_wsplit<<<32, 256, 0, stream>>>(W4, W4hi, W4lo);

  auto bn_fin_apply = [&](const float* g, const float* be, float slope) {
    k_bnfin<<<1, 128, 0, stream>>>(bnsum, bnsq, g, be, scaleb, shiftb, N);
    k_bnapply<<<((size_t)N * HD / 4 + 255) / 256, 256, 0, stream>>>(OUT, scaleb, shiftb, slope, Ab,
                                                                    (size_t)N * HD);
  };

  // ---- layer 1 (fi=3) ----
  k_prop3<<<nb, 256, 0, stream>>>(rowptr, col, wgt, x, nullptr, t1, 1.f, N);
  k_prop3<<<nb, 256, 0, stream>>>(rowptr, col, wgt, t1, x, t2, 2.f, N);
  k_prop3<<<nb, 256, 0, stream>>>(rowptr, col, wgt, t2, t1, t3, 2.f, N);
  k_l1gemm<<<((size_t)N * HD + 255) / 256, 256, 0, stream>>>(x, t1, t2, t3, W1, b1, OUT, N);
  hipMemsetAsync(bnsum, 0, HD * 4, stream);
  hipMemsetAsync(bnsq, 0, HD * 4, stream);
  k_bnstat<<<256, 256, 0, stream>>>(OUT, 0.01f, bnsum, bnsq, N);
  bn_fin_apply(g1, be1, 0.01f);

  // ---- layers 2..4 ----
  auto cheb_layer = [&](const uint4* Whi, const uint4* Wlo, const float* bk, bool stats,
                        float slope) {
    k_prop128<<<pb, 256, 0, stream>>>(rowptr, col, wgt, Ab, nullptr, Bb, 1.f, N);
    k_prop128<<<pb, 256, 0, stream>>>(rowptr, col, wgt, Bb, Ab, Cb, 2.f, N);
    k_prop128<<<pb, 256, 0, stream>>>(rowptr, col, wgt, Cb, Bb, OUT, 2.f, N);  // T3 -> OUT
    if (stats) {
      hipMemsetAsync(bnsum, 0, HD * 4, stream);
      hipMemsetAsync(bnsq, 0, HD * 4, stream);
    }
    k_gemm4m<<<gbm, 256, 0, stream>>>(Ab, Bb, Cb, OUT, Whi, Wlo, bk, OUT,
                                      stats ? bnsum : nullptr, stats ? bnsq : nullptr, slope, N);
  };

  cheb_layer(W2hi, W2lo, b2, true, 0.01f);
  bn_fin_apply(g2, be2, 0.01f);
  cheb_layer(W3hi, W3lo, b3, true, 0.0f);
  bn_fin_apply(g3, be3, 0.0f);
  cheb_layer(W4hi, W4lo, b4, false, 0.0f);

  // ---- L2 normalize + readout ----
  k_final<<<pb, 256, 0, stream>>>(OUT, Wr, br, out, N);
}